// Round 1
// baseline (311.198 us; speedup 1.0000x reference)
//
#include <hip/hip_runtime.h>
#include <math.h>

// Problem constants (from reference)
#define N_ROWS 8192
#define B_CH   64
#define L_SEQ  256
#define D_DIM  128
#define KEEP   64
#define HID    1024
#define KTOT   8320            // 128 (q) + 64*128 (packed); log_count handled in epilogue

// bf16 staging buffer layout (elements)
#define KOFF   (N_ROWS * D_DIM)            // 1,048,576  : start of k-chains
#define ZOFF   (KOFF + B_CH * L_SEQ * D_DIM) // 3,145,728 : zero page (128 elems)
#define BUF_ELEMS (ZOFF + 128)             // 3,145,856

typedef unsigned short ushort_t;
typedef __attribute__((ext_vector_type(8))) short  short8;   // 8 bf16 = 4 VGPRs (MFMA A/B frag)
typedef __attribute__((ext_vector_type(4))) float  float4v;  // MFMA C/D frag

// ---- helpers -------------------------------------------------------------

// fp32 -> bf16 round-to-nearest-even (inputs finite; no NaN handling needed)
__device__ __forceinline__ ushort_t f2bf(float f) {
    union { float f; unsigned int u; } v; v.f = f;
    unsigned int u = v.u;
    unsigned int r = u + 0x7fffu + ((u >> 16) & 1u);
    return (ushort_t)(r >> 16);
}

// async global->LDS, 16B per lane. LDS dest is wave-uniform base + lane*16;
// our lane->lds mapping is exactly contiguous in lane order (see staging map).
__device__ __forceinline__ void glds16(const void* g, void* l) {
    __builtin_amdgcn_global_load_lds(
        (const __attribute__((address_space(1))) unsigned int*)g,
        (__attribute__((address_space(3))) unsigned int*)l,
        16, 0, 0);
}

// ---- kernel 1: out[n] = b2 (atomic accumulation base; harness poisons d_out)
__global__ void init_out(float* __restrict__ out, const float* __restrict__ b2) {
    int i = blockIdx.x * blockDim.x + threadIdx.x;
    if (i < N_ROWS) out[i] = b2[0];
}

// ---- kernel 2: convert q,k to bf16 into buf; zero the zero-page ----------
__global__ void conv_qk(const float* __restrict__ q, const float* __restrict__ k,
                        ushort_t* __restrict__ buf) {
    int c = blockIdx.x * blockDim.x + threadIdx.x;
    if (c >= BUF_ELEMS / 8) return;
    int e = c * 8;
    float4 x0, x1;
    if (e < KOFF) {
        const float4* s = (const float4*)(q + e);
        x0 = s[0]; x1 = s[1];
    } else if (e < ZOFF) {
        const float4* s = (const float4*)(k + (e - KOFF));
        x0 = s[0]; x1 = s[1];
    } else {
        x0 = make_float4(0.f, 0.f, 0.f, 0.f);
        x1 = x0;
    }
    union { ushort_t s[8]; uint4 v; } o;
    o.s[0] = f2bf(x0.x); o.s[1] = f2bf(x0.y); o.s[2] = f2bf(x0.z); o.s[3] = f2bf(x0.w);
    o.s[4] = f2bf(x1.x); o.s[5] = f2bf(x1.y); o.s[6] = f2bf(x1.z); o.s[7] = f2bf(x1.w);
    *(uint4*)(buf + e) = o.v;
}

// ---- kernel 3: W1[0:8320,:] -> bf16 transposed w1t[h][k] (K-contiguous) --
__global__ void conv_w1t(const float* __restrict__ W1, ushort_t* __restrict__ w1t) {
    __shared__ float tile[64][65];   // +1 pad: transposed reads conflict-free
    const int k0 = blockIdx.x * 64, h0 = blockIdx.y * 64;
    const int t = threadIdx.x;
    const int hl = t & 63, kl = t >> 6;
#pragma unroll
    for (int i = 0; i < 16; ++i) {
        int kk = kl + i * 4;
        tile[kk][hl] = W1[(size_t)(k0 + kk) * HID + h0 + hl];
    }
    __syncthreads();
    const int kl2 = (t & 15) * 4, hl2 = t >> 4;
#pragma unroll
    for (int i = 0; i < 4; ++i) {
        int hh = hl2 + i * 16;
        union { ushort_t s[4]; uint2 v; } o;
#pragma unroll
        for (int j = 0; j < 4; ++j) o.s[j] = f2bf(tile[kl2 + j][hh]);
        *(uint2*)(w1t + (size_t)(h0 + hh) * KTOT + k0 + kl2) = o.v;
    }
}

// ---- kernel 4: first-64 masked positions per row -> gather offsets -------
__global__ void pack_idx(const int* __restrict__ mask, const int* __restrict__ batch_idx,
                         const int* __restrict__ count, int* __restrict__ srcoff,
                         float* __restrict__ logc) {
    const int n = blockIdx.x, t = threadIdx.x;
    __shared__ int sidx[KEEP];
    __shared__ int wcnt[4];
    if (t < KEEP) sidx[t] = -1;
    __syncthreads();
    const int m = (mask[n * L_SEQ + t] != 0) ? 1 : 0;
    unsigned long long bal = __ballot(m);
    const int w = t >> 6, l = t & 63;
    if (l == 0) wcnt[w] = (int)__popcll(bal);
    __syncthreads();
    int base = 0;
    for (int i = 0; i < w; ++i) base += wcnt[i];
    const int rank = base + (int)__popcll(bal & ((1ull << l) - 1ull));
    if (m && rank < KEEP) sidx[rank] = t;
    __syncthreads();
    if (t < KEEP) {
        int s = sidx[t];
        int b = batch_idx[n];
        srcoff[n * KEEP + t] = (s >= 0) ? (KOFF + (b * L_SEQ + s) * D_DIM) : ZOFF;
    }
    if (t == 64) logc[n] = log1pf((float)count[n]);
}

// ---- kernel 5: fused gather-GEMM + gelu + @W2 epilogue -------------------
// C-tile 128(n) x 128(h), BK=32, 4 waves in 2x2, each wave 4x4 MFMA 16x16x32.
// A rows gathered through srcoff (BK=32 divides D=128 -> one source block per K-tile).
__global__ void gemm_mlp(const ushort_t* __restrict__ buf, const ushort_t* __restrict__ w1t,
                         const int* __restrict__ srcoff, const float* __restrict__ logc,
                         const float* __restrict__ W1, const float* __restrict__ b1,
                         const float* __restrict__ W2, float* __restrict__ out) {
    __shared__ ushort_t As[128 * 32];   // [row][k] K-contiguous, 8 KB
    __shared__ ushort_t Bs[128 * 32];   // [h][k]   K-contiguous, 8 KB

    const int t = threadIdx.x;
    const int blkM = blockIdx.x, blkH = blockIdx.y;
    const int wave = t >> 6, lane = t & 63;
    const int wm = wave >> 1, wh = wave & 1;
    const int ln = lane & 15, quad = lane >> 4;

    float4v acc[4][4];
#pragma unroll
    for (int i = 0; i < 4; ++i)
#pragma unroll
        for (int j = 0; j < 4; ++j)
#pragma unroll
            for (int r = 0; r < 4; ++r) acc[i][j][r] = 0.0f;

    // staging map: chunk c in [0,512): LDS bytes [c*16, c*16+16) = row c>>2, 16B piece c&3
    const int c0 = t, c1 = t + 256;
    const int rA0 = c0 >> 2, q0 = c0 & 3;
    const int rA1 = c1 >> 2, q1 = c1 & 3;
    const int n0 = blkM * 128 + rA0, n1 = blkM * 128 + rA1;
    const int h0 = blkH * 128 + rA0, h1 = blkH * 128 + rA1;
    const int* so0 = srcoff + n0 * KEEP;
    const int* so1 = srcoff + n1 * KEEP;
    const ushort_t* gB0 = w1t + (size_t)h0 * KTOT + q0 * 8;
    const ushort_t* gB1 = w1t + (size_t)h1 * KTOT + q1 * 8;
    ushort_t* lA0 = As + c0 * 8;
    ushort_t* lA1 = As + c1 * 8;
    ushort_t* lB0 = Bs + c0 * 8;
    ushort_t* lB1 = Bs + c1 * 8;

    for (int bi = 0; bi < 65; ++bi) {            // 65 source blocks (q + 64 gathered)
        const int oA0 = (bi == 0) ? (n0 * D_DIM) : so0[bi - 1];
        const int oA1 = (bi == 0) ? (n1 * D_DIM) : so1[bi - 1];
#pragma unroll
        for (int s4 = 0; s4 < 4; ++s4) {         // 4 K-tiles of 32 per block
            const int kt = bi * 4 + s4;
            const int inner = s4 * 32;
            glds16(buf + oA0 + inner + q0 * 8, lA0);
            glds16(buf + oA1 + inner + q1 * 8, lA1);
            glds16(gB0 + kt * 32, lB0);
            glds16(gB1 + kt * 32, lB1);
            __syncthreads();                     // drains vmcnt (global_load_lds)
            short8 af[4], bfr[4];
#pragma unroll
            for (int mi = 0; mi < 4; ++mi)
                af[mi] = *(const short8*)(As + (wm * 64 + mi * 16 + ln) * 32 + quad * 8);
#pragma unroll
            for (int ni = 0; ni < 4; ++ni)
                bfr[ni] = *(const short8*)(Bs + (wh * 64 + ni * 16 + ln) * 32 + quad * 8);
#pragma unroll
            for (int mi = 0; mi < 4; ++mi)
#pragma unroll
                for (int ni = 0; ni < 4; ++ni)
                    acc[mi][ni] = __builtin_amdgcn_mfma_f32_16x16x32_bf16(
                        af[mi], bfr[ni], acc[mi][ni], 0, 0, 0);
            __syncthreads();
        }
    }

    // Epilogue: pre = acc + logc[n]*W1[last,h] + b1[h]; gelu(exact); dot with W2; atomic out.
    // C/D layout (verified m89/m91): col = lane&15, row = quad*4 + reg.
    const float* w1last = W1 + (size_t)KTOT * HID;
    float w1l[4], b1v[4], w2v[4];
#pragma unroll
    for (int ni = 0; ni < 4; ++ni) {
        int h = blkH * 128 + wh * 64 + ni * 16 + ln;
        w1l[ni] = w1last[h];
        b1v[ni] = b1[h];
        w2v[ni] = W2[h];
    }
    const int nbase = blkM * 128 + wm * 64 + quad * 4;
#pragma unroll
    for (int mi = 0; mi < 4; ++mi) {
#pragma unroll
        for (int rg = 0; rg < 4; ++rg) {
            const int n = nbase + mi * 16 + rg;
            const float lc = logc[n];
            float s = 0.0f;
#pragma unroll
            for (int ni = 0; ni < 4; ++ni) {
                float pre = acc[mi][ni][rg] + lc * w1l[ni] + b1v[ni];
                float hv = 0.5f * pre * (1.0f + erff(pre * 0.70710678118654752f));
                s += hv * w2v[ni];
            }
            // reduce the 16 lanes of this quad (same n, 64 h-columns total)
            s += __shfl_xor(s, 1);
            s += __shfl_xor(s, 2);
            s += __shfl_xor(s, 4);
            s += __shfl_xor(s, 8);
            if (ln == 0) atomicAdd(out + n, s);
        }
    }
}

// ---- launch --------------------------------------------------------------
extern "C" void kernel_launch(void* const* d_in, const int* in_sizes, int n_in,
                              void* d_out, int out_size, void* d_ws, size_t ws_size,
                              hipStream_t stream) {
    const float* q     = (const float*)d_in[0];
    const float* k     = (const float*)d_in[1];
    const int*   bidx  = (const int*)d_in[2];
    const int*   mask  = (const int*)d_in[3];
    const int*   count = (const int*)d_in[4];
    const float* W1    = (const float*)d_in[5];
    const float* b1    = (const float*)d_in[6];
    const float* W2    = (const float*)d_in[7];
    const float* b2    = (const float*)d_in[8];
    float* out = (float*)d_out;

    // workspace layout (bytes): buf 6,291,712 | w1t 17,039,360 | srcoff 2,097,152 | logc 32,768
    char* ws = (char*)d_ws;
    ushort_t* buf    = (ushort_t*)(ws);
    ushort_t* w1t    = (ushort_t*)(ws + 6291712);
    int*      srcoff = (int*)(ws + 6291712 + 17039360);
    float*    logc   = (float*)(ws + 6291712 + 17039360 + 2097152);

    init_out<<<(N_ROWS + 255) / 256, 256, 0, stream>>>(out, b2);
    conv_qk<<<(BUF_ELEMS / 8 + 255) / 256, 256, 0, stream>>>(q, k, buf);
    conv_w1t<<<dim3(KTOT / 64, HID / 64), 256, 0, stream>>>(W1, w1t);
    pack_idx<<<N_ROWS, 256, 0, stream>>>(mask, bidx, count, srcoff, logc);
    gemm_mlp<<<dim3(N_ROWS / 128, HID / 128), 256, 0, stream>>>(
        buf, w1t, srcoff, logc, W1, b1, W2, out);
}

// Round 2
// 259.419 us; speedup vs baseline: 1.1996x; 1.1996x over previous
//
#include <hip/hip_runtime.h>
#include <math.h>

// Problem constants (from reference)
#define N_ROWS 8192
#define B_CH   64
#define L_SEQ  256
#define D_DIM  128
#define KEEP   64
#define HID    1024
#define KTOT   8320            // 128 (q) + 64*128 (packed); log_count handled in epilogue

// bf16 staging buffer layout (elements)
#define KOFF   (N_ROWS * D_DIM)              // 1,048,576  : start of k-chains
#define ZOFF   (KOFF + B_CH * L_SEQ * D_DIM) // 3,145,728  : zero page (128 elems)
#define BUF_ELEMS (ZOFF + 128)               // 3,145,856

typedef unsigned short ushort_t;
typedef __attribute__((ext_vector_type(8))) short  short8;   // 8 bf16 = 4 VGPRs (MFMA A/B frag)
typedef __attribute__((ext_vector_type(4))) float  float4v;  // MFMA C/D frag

// ---- helpers -------------------------------------------------------------

// fp32 -> bf16 round-to-nearest-even (inputs finite; no NaN handling needed)
__device__ __forceinline__ ushort_t f2bf(float f) {
    union { float f; unsigned int u; } v; v.f = f;
    unsigned int u = v.u;
    unsigned int r = u + 0x7fffu + ((u >> 16) & 1u);
    return (ushort_t)(r >> 16);
}

// async global->LDS, 16B per lane. LDS dest is wave-uniform base + lane*16;
// lane->lds mapping below is exactly contiguous in lane order per pass.
__device__ __forceinline__ void glds16(const void* g, void* l) {
    __builtin_amdgcn_global_load_lds(
        (const __attribute__((address_space(1))) unsigned int*)g,
        (__attribute__((address_space(3))) unsigned int*)l,
        16, 0, 0);
}

// ---- kernel 1: out[n] = b2 (atomic accumulation base; harness poisons d_out)
__global__ void init_out(float* __restrict__ out, const float* __restrict__ b2) {
    int i = blockIdx.x * blockDim.x + threadIdx.x;
    if (i < N_ROWS) out[i] = b2[0];
}

// ---- kernel 2: convert q,k to bf16 into buf; zero the zero-page ----------
__global__ void conv_qk(const float* __restrict__ q, const float* __restrict__ k,
                        ushort_t* __restrict__ buf) {
    int c = blockIdx.x * blockDim.x + threadIdx.x;
    if (c >= BUF_ELEMS / 8) return;
    int e = c * 8;
    float4 x0, x1;
    if (e < KOFF) {
        const float4* s = (const float4*)(q + e);
        x0 = s[0]; x1 = s[1];
    } else if (e < ZOFF) {
        const float4* s = (const float4*)(k + (e - KOFF));
        x0 = s[0]; x1 = s[1];
    } else {
        x0 = make_float4(0.f, 0.f, 0.f, 0.f);
        x1 = x0;
    }
    union { ushort_t s[8]; uint4 v; } o;
    o.s[0] = f2bf(x0.x); o.s[1] = f2bf(x0.y); o.s[2] = f2bf(x0.z); o.s[3] = f2bf(x0.w);
    o.s[4] = f2bf(x1.x); o.s[5] = f2bf(x1.y); o.s[6] = f2bf(x1.z); o.s[7] = f2bf(x1.w);
    *(uint4*)(buf + e) = o.v;
}

// ---- kernel 3: W1[0:8320,:] -> bf16 transposed w1t[h][k], 16B coalesced writes
__global__ void conv_w1t(const float* __restrict__ W1, ushort_t* __restrict__ w1t) {
    __shared__ float tile[64][65];   // +1 pad: transposed reads 2-way max
    const int k0 = blockIdx.x * 64, h0 = blockIdx.y * 64;
    const int t = threadIdx.x;
    const int hl = t & 63, kl = t >> 6;
#pragma unroll
    for (int i = 0; i < 16; ++i) {
        int kk = kl + i * 4;
        tile[kk][hl] = W1[(size_t)(k0 + kk) * HID + h0 + hl];
    }
    __syncthreads();
    // 512 chunks: 64 h-rows x 8 pieces of 8 bf16 (16 B); 2 chunks/thread
#pragma unroll
    for (int i = 0; i < 2; ++i) {
        int chunk = i * 256 + t;
        int h = chunk >> 3, piece = chunk & 7;
        union { ushort_t s[8]; uint4 v; } o;
#pragma unroll
        for (int j = 0; j < 8; ++j) o.s[j] = f2bf(tile[piece * 8 + j][h]);
        *(uint4*)(w1t + (size_t)(h0 + h) * KTOT + k0 + piece * 8) = o.v;
    }
}

// ---- kernel 4: first-64 masked positions per row -> srcLUT[65][N_ROWS] ---
// srcLUT[0][n] = q-row offset; srcLUT[1+j][n] = j-th picked key block offset (or ZOFF)
__global__ void pack_idx(const int* __restrict__ mask, const int* __restrict__ batch_idx,
                         const int* __restrict__ count, int* __restrict__ srcLUT,
                         float* __restrict__ logc) {
    const int n = blockIdx.x, t = threadIdx.x;
    __shared__ int sidx[KEEP];
    __shared__ int wcnt[4];
    if (t < KEEP) sidx[t] = -1;
    __syncthreads();
    const int m = (mask[n * L_SEQ + t] != 0) ? 1 : 0;
    unsigned long long bal = __ballot(m);
    const int w = t >> 6, l = t & 63;
    if (l == 0) wcnt[w] = (int)__popcll(bal);
    __syncthreads();
    int base = 0;
    for (int i = 0; i < w; ++i) base += wcnt[i];
    const int rank = base + (int)__popcll(bal & ((1ull << l) - 1ull));
    if (m && rank < KEEP) sidx[rank] = t;
    __syncthreads();
    if (t < KEEP) {
        int s = sidx[t];
        int b = batch_idx[n];
        srcLUT[(t + 1) * N_ROWS + n] = (s >= 0) ? (KOFF + (b * L_SEQ + s) * D_DIM) : ZOFF;
    }
    if (t == 64) logc[n] = log1pf((float)count[n]);
    if (t == 65) srcLUT[n] = n * D_DIM;
}

// ---- kernel 5: fused gather-GEMM + gelu + @W2 epilogue -------------------
// C-tile 128(n) x 128(h), BK=128 (one gathered source block per iteration),
// 4 waves in 2x2, each wave 4x4 MFMA 16x16x32 per 32-wide k-step (4 steps/iter).
// LDS 16B-slot XOR swizzle (slot ^= row&15) -> conflict-free ds_read_b128.
__global__ __launch_bounds__(256, 2)
void gemm_mlp(const ushort_t* __restrict__ buf, const ushort_t* __restrict__ w1t,
              const int* __restrict__ srcLUT, const float* __restrict__ logc,
              const float* __restrict__ W1, const float* __restrict__ b1,
              const float* __restrict__ W2, float* __restrict__ out) {
    __shared__ ushort_t As[128 * 128];   // 32 KB, [row][k] with slot-swizzle
    __shared__ ushort_t Bs[128 * 128];   // 32 KB

    const int t = threadIdx.x;
    const int blkM = blockIdx.x, blkH = blockIdx.y;
    const int wave = t >> 6, lane = t & 63;
    const int wm = wave >> 1, wh = wave & 1;
    const int ln = lane & 15, quad = lane >> 4;

    float4v acc[4][4];
#pragma unroll
    for (int i = 0; i < 4; ++i)
#pragma unroll
        for (int j = 0; j < 4; ++j)
#pragma unroll
            for (int r = 0; r < 4; ++r) acc[i][j][r] = 0.0f;

    // Staging map: pass i (0..7), thread t handles chunk c = i*256 + t.
    // row = c>>4 = i*16 + (t>>4); LDS slot = t&15; global piece = slot ^ (row&15).
    // row&15 == t>>4 for all passes, so the swizzled piece index is pass-invariant.
    const int tr = t >> 4;            // row sub-index (0..15)
    const int slot = t & 15;
    const int pg = slot ^ tr;         // global 16B piece to fetch
    ushort_t* lA = As + t * 8;        // + i*2048 per pass
    ushort_t* lB = Bs + t * 8;
    const ushort_t* gB[8];
#pragma unroll
    for (int i = 0; i < 8; ++i)
        gB[i] = w1t + (size_t)(blkH * 128 + i * 16 + tr) * KTOT + pg * 8;
    const int* lutBase = srcLUT + blkM * 128 + tr;

    int offA[8];
#pragma unroll
    for (int i = 0; i < 8; ++i) offA[i] = lutBase[i * 16];   // bi = 0 (q rows)

    for (int bi = 0; bi < 65; ++bi) {
#pragma unroll
        for (int i = 0; i < 8; ++i) {
            glds16(buf + offA[i] + pg * 8, lA + i * 2048);
            glds16(gB[i] + bi * 128, lB + i * 2048);
        }
        // prefetch next iteration's gather offsets (hidden under the barrier drain)
        int offN[8];
        if (bi < 64) {
#pragma unroll
            for (int i = 0; i < 8; ++i) offN[i] = lutBase[(bi + 1) * N_ROWS + i * 16];
        }
        __syncthreads();                      // drains vmcnt (global_load_lds)
#pragma unroll
        for (int kk = 0; kk < 4; ++kk) {
            short8 af[4], bfr[4];
#pragma unroll
            for (int mi = 0; mi < 4; ++mi) {
                const int row = wm * 64 + mi * 16 + ln;          // row&15 == ln
                const int sl = (kk * 4 + quad) ^ ln;
                af[mi] = *(const short8*)(As + row * 128 + sl * 8);
            }
#pragma unroll
            for (int ni = 0; ni < 4; ++ni) {
                const int row = wh * 64 + ni * 16 + ln;
                const int sl = (kk * 4 + quad) ^ ln;
                bfr[ni] = *(const short8*)(Bs + row * 128 + sl * 8);
            }
#pragma unroll
            for (int mi = 0; mi < 4; ++mi)
#pragma unroll
                for (int ni = 0; ni < 4; ++ni)
                    acc[mi][ni] = __builtin_amdgcn_mfma_f32_16x16x32_bf16(
                        af[mi], bfr[ni], acc[mi][ni], 0, 0, 0);
        }
        __syncthreads();
#pragma unroll
        for (int i = 0; i < 8; ++i) offA[i] = offN[i];
    }

    // Epilogue: pre = acc + logc[n]*W1[last,h] + b1[h]; gelu(exact); dot W2; atomic out.
    // C/D layout (verified m89/m91): col = lane&15, row = quad*4 + reg.
    const float* w1last = W1 + (size_t)KTOT * HID;
    float w1l[4], b1v[4], w2v[4];
#pragma unroll
    for (int ni = 0; ni < 4; ++ni) {
        int h = blkH * 128 + wh * 64 + ni * 16 + ln;
        w1l[ni] = w1last[h];
        b1v[ni] = b1[h];
        w2v[ni] = W2[h];
    }
    const int nbase = blkM * 128 + wm * 64 + quad * 4;
#pragma unroll
    for (int mi = 0; mi < 4; ++mi) {
#pragma unroll
        for (int rg = 0; rg < 4; ++rg) {
            const int n = nbase + mi * 16 + rg;
            const float lc = logc[n];
            float s = 0.0f;
#pragma unroll
            for (int ni = 0; ni < 4; ++ni) {
                float pre = acc[mi][ni][rg] + lc * w1l[ni] + b1v[ni];
                float hv = 0.5f * pre * (1.0f + erff(pre * 0.70710678118654752f));
                s += hv * w2v[ni];
            }
            // reduce the 16 lanes of this quad (same n, 64 h-columns total)
            s += __shfl_xor(s, 1);
            s += __shfl_xor(s, 2);
            s += __shfl_xor(s, 4);
            s += __shfl_xor(s, 8);
            if (ln == 0) atomicAdd(out + n, s);
        }
    }
}

// ---- launch --------------------------------------------------------------
extern "C" void kernel_launch(void* const* d_in, const int* in_sizes, int n_in,
                              void* d_out, int out_size, void* d_ws, size_t ws_size,
                              hipStream_t stream) {
    const float* q     = (const float*)d_in[0];
    const float* k     = (const float*)d_in[1];
    const int*   bidx  = (const int*)d_in[2];
    const int*   mask  = (const int*)d_in[3];
    const int*   count = (const int*)d_in[4];
    const float* W1    = (const float*)d_in[5];
    const float* b1    = (const float*)d_in[6];
    const float* W2    = (const float*)d_in[7];
    const float* b2    = (const float*)d_in[8];
    float* out = (float*)d_out;

    // workspace layout (bytes): buf 6,291,712 | w1t 17,039,360 | srcLUT 2,129,920 | logc 32,768
    char* ws = (char*)d_ws;
    ushort_t* buf    = (ushort_t*)(ws);
    ushort_t* w1t    = (ushort_t*)(ws + 6291712);
    int*      srcLUT = (int*)(ws + 6291712 + 17039360);
    float*    logc   = (float*)(ws + 6291712 + 17039360 + 2129920);

    init_out<<<(N_ROWS + 255) / 256, 256, 0, stream>>>(out, b2);
    conv_qk<<<(BUF_ELEMS / 8 + 255) / 256, 256, 0, stream>>>(q, k, buf);
    conv_w1t<<<dim3(KTOT / 64, HID / 64), 256, 0, stream>>>(W1, w1t);
    pack_idx<<<N_ROWS, 256, 0, stream>>>(mask, bidx, count, srcLUT, logc);
    gemm_mlp<<<dim3(N_ROWS / 128, HID / 128), 256, 0, stream>>>(
        buf, w1t, srcLUT, logc, W1, b1, W2, out);
}